// Round 4
// baseline (64.489 us; speedup 1.0000x reference)
//
#include <hip/hip_runtime.h>

// x [E=512][N=65536] fp32.
//   sum_abs[col] = sum_{e>=1} |x[e][col]|
//   lb = x0 - sum_abs; ub = x0 + sum_abs
//   crossing = lb<=0 && ub>=0 ; dead = ub<=0
//   alpha = crossing ? 1-lb : 1
//   out[0]   = dead?0 : crossing? alpha*x0 - alpha*lb*0.5 : x0
//   out[e>0] = dead?0 : crossing? alpha*x : x
//
// Two-phase within one block, cache-backed re-read:
//   phase 1: reduce |x| over the block's 32-col slab (wave shuffle + tiny LDS)
//   phase 2: re-read the slab (hot in L2/L3 -- this block just fetched it),
//            scale, store.
// No LDS data slab, no registers live across the barrier -> ~32 waves/CU.

#define EROWS 512
#define W4 8                    // float4 column-groups per block (32 cols)
#define BLK 256
#define RSTRIDE (BLK / W4)      // 32 rows between a thread's samples
#define RPT (EROWS / RSTRIDE)   // 16 float4 per thread per phase
#define NWAVES (BLK / 64)       // 4

__global__ __launch_bounds__(BLK) void ar_fused(const float* __restrict__ x,
                                                float* __restrict__ out, int n4) {
    __shared__ float4 part[NWAVES][W4];   // per-wave per-cseg partials (512 B)
    __shared__ float4 scale4[W4];

    int t = threadIdx.x;
    int cseg  = t & (W4 - 1);             // 0..7
    int rbase = t >> 3;                   // 0..31
    int col4 = blockIdx.x * W4 + cseg;

    const float4* xv = (const float4*)x;
    float4* ov = (float4*)out;

    // ---- phase 1: reduce sum|x| over rows 1..511 for this cseg
    float4 acc = {0.f, 0.f, 0.f, 0.f};
    #pragma unroll
    for (int k = 0; k < RPT; ++k) {
        int row = rbase + k * RSTRIDE;
        float4 v = xv[(size_t)row * n4 + col4];
        if (row != 0) {
            acc.x += fabsf(v.x); acc.y += fabsf(v.y);
            acc.z += fabsf(v.z); acc.w += fabsf(v.w);
        }
    }
    // wave-level reduce: lanes sharing cseg sit at stride 8 within the wave
    #pragma unroll
    for (int d = W4; d < 64; d <<= 1) {
        acc.x += __shfl_xor(acc.x, d);
        acc.y += __shfl_xor(acc.y, d);
        acc.z += __shfl_xor(acc.z, d);
        acc.w += __shfl_xor(acc.w, d);
    }
    if ((t & 63) < W4) part[t >> 6][cseg] = acc;
    __syncthreads();

    // ---- finalize: 8 threads, one per float4 col group
    if (t < W4) {
        float4 s = {0.f, 0.f, 0.f, 0.f};
        #pragma unroll
        for (int w = 0; w < NWAVES; ++w) {
            float4 p = part[w][t];
            s.x += p.x; s.y += p.y; s.z += p.z; s.w += p.w;
        }
        float4 x0v = xv[blockIdx.x * W4 + t];   // row 0 (L2-hot)
        float x0[4] = {x0v.x, x0v.y, x0v.z, x0v.w};
        float sm[4] = {s.x, s.y, s.z, s.w};
        float sc[4], o0[4];
        #pragma unroll
        for (int j = 0; j < 4; ++j) {
            float lb = x0[j] - sm[j];
            float ub = x0[j] + sm[j];
            bool crossing = (lb <= 0.f) && (ub >= 0.f);
            bool dead = (ub <= 0.f);
            float alpha = crossing ? (1.f - lb) : 1.f;
            float scl = dead ? 0.f : (crossing ? alpha : 1.f);
            float addv = (crossing && !dead) ? (-alpha * lb * 0.5f) : 0.f;
            sc[j] = scl;
            o0[j] = scl * x0[j] + addv;
        }
        float4 scv = {sc[0], sc[1], sc[2], sc[3]};
        float4 o0v = {o0[0], o0[1], o0[2], o0[3]};
        scale4[t] = scv;
        ov[blockIdx.x * W4 + t] = o0v;          // row 0 output
    }
    __syncthreads();

    // ---- phase 2: re-read slab (cache-hot), scale, store rows 1..511
    float4 s = scale4[cseg];
    #pragma unroll
    for (int k = 0; k < RPT; ++k) {
        int row = rbase + k * RSTRIDE;
        if (row == 0) continue;                 // row 0 already written
        float4 v = xv[(size_t)row * n4 + col4];
        float4 o;
        o.x = v.x * s.x; o.y = v.y * s.y;
        o.z = v.z * s.z; o.w = v.w * s.w;
        ov[(size_t)row * n4 + col4] = o;
    }
}

extern "C" void kernel_launch(void* const* d_in, const int* in_sizes, int n_in,
                              void* d_out, int out_size, void* d_ws, size_t ws_size,
                              hipStream_t stream) {
    const float* x = (const float*)d_in[0];
    float* out = (float*)d_out;
    int total = in_sizes[0];     // 512 * 65536
    int N = total / EROWS;       // 65536
    int n4 = N >> 2;             // 16384 float4 per row
    int nblocks = n4 / W4;       // 2048

    ar_fused<<<nblocks, BLK, 0, stream>>>(x, out, n4);
}

// Round 5
// 46.597 us; speedup vs baseline: 1.3840x; 1.3840x over previous
//
#include <hip/hip_runtime.h>

// x [E=512][N=65536] fp32.
//   sum_abs[col] = sum_{e>=1} |x[e][col]|
//   lb = x0 - sum_abs; ub = x0 + sum_abs
//   crossing = lb<=0 && ub>=0 ; dead = ub<=0
//   alpha = crossing ? 1-lb : 1
//   out[0]   = dead?0 : crossing? alpha*x0 - alpha*lb*0.5 : x0
//   out[e>0] = dead?0 : crossing? alpha*x : x
//
// R2 structure (single global read, LDS slab) + BLK=1024 for occupancy:
// 66 KiB LDS -> 2 blocks/CU, but 16 waves/block -> 32 waves/CU (4x R2).
// Grid = 512 blocks = exactly 2 per CU.

#define EROWS 512
#define W4 8                    // float4 column-groups per block (32 cols)
#define BLK 1024
#define RSTRIDE (BLK / W4)      // 128 rows between a thread's samples
#define RPT (EROWS / RSTRIDE)   // 4 float4 per thread
#define NWAVES (BLK / 64)       // 16

__global__ __launch_bounds__(BLK) void ar_fused(const float* __restrict__ x,
                                                float* __restrict__ out, int n4) {
    __shared__ float4 slab[EROWS * W4];    // 64 KiB [row][cseg]
    __shared__ float4 part[NWAVES][W4];    // 2 KiB per-wave partials
    __shared__ float4 scale4[W4];

    int t = threadIdx.x;
    int cseg  = t & (W4 - 1);              // 0..7
    int rbase = t >> 3;                    // 0..127
    int col4 = blockIdx.x * W4 + cseg;

    const float4* xv = (const float4*)x;
    float4* ov = (float4*)out;

    // ---- single global read: stage to LDS + accumulate |x| (row 0 excluded)
    float4 acc = {0.f, 0.f, 0.f, 0.f};
    #pragma unroll
    for (int k = 0; k < RPT; ++k) {
        int row = rbase + k * RSTRIDE;
        float4 v = xv[(size_t)row * n4 + col4];
        slab[row * W4 + cseg] = v;
        if (row != 0) {                    // only t<8,k=0 excluded
            acc.x += fabsf(v.x); acc.y += fabsf(v.y);
            acc.z += fabsf(v.z); acc.w += fabsf(v.w);
        }
    }
    // wave-level reduce: lanes sharing a cseg sit at stride 8 within the wave
    #pragma unroll
    for (int d = W4; d < 64; d <<= 1) {
        acc.x += __shfl_xor(acc.x, d);
        acc.y += __shfl_xor(acc.y, d);
        acc.z += __shfl_xor(acc.z, d);
        acc.w += __shfl_xor(acc.w, d);
    }
    if ((t & 63) < W4) part[t >> 6][cseg] = acc;
    __syncthreads();

    // ---- finalize: 8 threads, one per float4 col group
    if (t < W4) {
        float4 s = {0.f, 0.f, 0.f, 0.f};
        #pragma unroll
        for (int w = 0; w < NWAVES; ++w) {
            float4 p = part[w][t];
            s.x += p.x; s.y += p.y; s.z += p.z; s.w += p.w;
        }
        float4 x0v = slab[t];              // row 0, col group t
        float x0[4] = {x0v.x, x0v.y, x0v.z, x0v.w};
        float sm[4] = {s.x, s.y, s.z, s.w};
        float sc[4], o0[4];
        #pragma unroll
        for (int j = 0; j < 4; ++j) {
            float lb = x0[j] - sm[j];
            float ub = x0[j] + sm[j];
            bool crossing = (lb <= 0.f) && (ub >= 0.f);
            bool dead = (ub <= 0.f);
            float alpha = crossing ? (1.f - lb) : 1.f;
            float scl = dead ? 0.f : (crossing ? alpha : 1.f);
            float addv = (crossing && !dead) ? (-alpha * lb * 0.5f) : 0.f;
            sc[j] = scl;
            o0[j] = scl * x0[j] + addv;
        }
        float4 scv = {sc[0], sc[1], sc[2], sc[3]};
        float4 o0v = {o0[0], o0[1], o0[2], o0[3]};
        scale4[t] = scv;
        ov[col4] = o0v;                    // row 0 output (col4 == blockIdx*8+t)
    }
    __syncthreads();

    // ---- rescale from LDS, write out rows 1..511
    float4 s = scale4[cseg];
    #pragma unroll
    for (int k = 0; k < RPT; ++k) {
        int row = rbase + k * RSTRIDE;
        if (row == 0) continue;            // row 0 already written
        float4 v = slab[row * W4 + cseg];
        float4 o;
        o.x = v.x * s.x; o.y = v.y * s.y;
        o.z = v.z * s.z; o.w = v.w * s.w;
        ov[(size_t)row * n4 + col4] = o;
    }
}

extern "C" void kernel_launch(void* const* d_in, const int* in_sizes, int n_in,
                              void* d_out, int out_size, void* d_ws, size_t ws_size,
                              hipStream_t stream) {
    const float* x = (const float*)d_in[0];
    float* out = (float*)d_out;
    int total = in_sizes[0];     // 512 * 65536
    int N = total / EROWS;       // 65536
    int n4 = N >> 2;             // 16384 float4 per row
    int nblocks = n4 / W4;       // 512

    ar_fused<<<nblocks, BLK, 0, stream>>>(x, out, n4);
}